// Round 1
// baseline (1854.282 us; speedup 1.0000x reference)
//
#include <hip/hip_runtime.h>
#include <hip/hip_bf16.h>
#include <stdint.h>

#define G_    1024
#define NPG   64
#define EPG   256
#define N_    (G_*NPG)     // 65536
#define E_    (G_*EPG)     // 262144
#define IN_CH 768
#define CH    128
#define KSEL  128
#define HID   512          // 4*CH

// ---- output layout (element offsets, all float32) ----
#define NCH  (N_*CH)       // 8388608
#define GK   (G_*KSEL)     // 131072
#define OFF0 0
#define OFF1 (OFF0 + NCH)
#define OFF2 (OFF1 + 2*GK)
#define OFF3 (OFF2 + GK)
#define OFF4 (OFF3 + GK)
#define OFF5 (OFF4 + N_)
#define OFF6 (OFF5 + NCH)
#define OFF7 (OFF6 + 2*GK)
#define OFF8 (OFF7 + GK)
#define OFF9 (OFF8 + GK)
#define OFF10 (OFF9 + N_)

__global__ void k_deg(const int* __restrict__ ei, const float* __restrict__ ea,
                      float* __restrict__ deg) {
    int e = blockIdx.x * 256 + threadIdx.x;
    if (e < E_) atomicAdd(&deg[ei[E_ + e]], ea[e]);
}

__global__ void k_dis(float* __restrict__ deg) {
    int i = blockIdx.x * 256 + threadIdx.x;
    if (i < N_) { float d = deg[i]; deg[i] = d > 0.f ? 1.0f / sqrtf(d) : 0.f; }
}

__global__ void k_norm(const int* __restrict__ ei, const float* __restrict__ ea,
                       const float* __restrict__ dis, float* __restrict__ norm) {
    int e = blockIdx.x * 256 + threadIdx.x;
    if (e < E_) norm[e] = dis[ei[e]] * ea[e] * dis[ei[E_ + e]];
}

// Build concatenated weights: WV1 = [W1|V1] (768x256), WV2 = [W2|V2] (128x256),
// Mw (128x1024): cols 0..511 = mw1 rows 0..127, cols 512..1023 = mw1 rows 128..255.
__global__ void k_concat(const float* __restrict__ W1, const float* __restrict__ V1,
                         const float* __restrict__ W2, const float* __restrict__ V2,
                         const float* __restrict__ mw1,
                         float* __restrict__ WV1, float* __restrict__ WV2,
                         float* __restrict__ Mw) {
    int i = blockIdx.x * 256 + threadIdx.x;
    if (i < IN_CH * 2 * CH) {
        int r = i >> 8, c = i & 255;
        WV1[i] = (c < CH) ? W1[r*CH + c] : V1[r*CH + (c - CH)];
    }
    if (i < CH * 2 * CH) {
        int r = i >> 8, c = i & 255;
        WV2[i] = (c < CH) ? W2[r*CH + c] : V2[r*CH + (c - CH)];
    }
    if (i < CH * 2 * HID) {
        int r = i >> 10, c = i & 1023;
        Mw[i] = (c < HID) ? mw1[r*HID + c] : mw1[(CH + r)*HID + (c - HID)];
    }
}

// simple fp32 shared-memory tiled GEMM: C(MxN) = A(MxK) @ B(KxN), row-major
template<bool BF16_OUT>
__global__ __launch_bounds__(256) void gemm_kernel(const float* __restrict__ A,
                                                   const float* __restrict__ B,
                                                   void* __restrict__ C,
                                                   int M, int N, int K) {
    const int BM = 64, BN = 64, BK = 16;
    __shared__ float As[BK][BM];
    __shared__ float Bs[BK][BN];
    int bm = blockIdx.x * BM;
    int bn = blockIdx.y * BN;
    int t  = threadIdx.x;
    int tx = t & 15, ty = t >> 4;
    float acc[4][4] = {};
    for (int k0 = 0; k0 < K; k0 += BK) {
        #pragma unroll
        for (int l = t; l < BM*BK; l += 256) {
            int m = l >> 4, k = l & 15;
            As[k][m] = A[(size_t)(bm + m) * K + k0 + k];
        }
        #pragma unroll
        for (int l = t; l < BK*BN; l += 256) {
            int k = l >> 6, n = l & 63;
            Bs[k][n] = B[(size_t)(k0 + k) * N + bn + n];
        }
        __syncthreads();
        #pragma unroll
        for (int k = 0; k < BK; ++k) {
            float a[4], b[4];
            #pragma unroll
            for (int i = 0; i < 4; ++i) a[i] = As[k][ty*4 + i];
            #pragma unroll
            for (int j = 0; j < 4; ++j) b[j] = Bs[k][tx*4 + j];
            #pragma unroll
            for (int i = 0; i < 4; ++i)
                #pragma unroll
                for (int j = 0; j < 4; ++j)
                    acc[i][j] += a[i] * b[j];
        }
        __syncthreads();
    }
    #pragma unroll
    for (int i = 0; i < 4; ++i) {
        size_t m = bm + ty*4 + i;
        #pragma unroll
        for (int j = 0; j < 4; ++j) {
            size_t n = bn + tx*4 + j;
            if (BF16_OUT) ((__hip_bfloat16*)C)[m * N + n] = __float2bfloat16(acc[i][j]);
            else          ((float*)C)[m * N + n] = acc[i][j];
        }
    }
}

// agg[col] += norm * m[row];  B holds [m|v] (Nx256), m = cols 0..127
__global__ void k_scatter(const int* __restrict__ ei, const float* __restrict__ norm,
                          const float* __restrict__ B, float* __restrict__ agg) {
    int gid = blockIdx.x * 256 + threadIdx.x;   // E_*32 threads
    int e  = gid >> 5;
    int c4 = (gid & 31) << 2;
    if (e >= E_) return;
    int r = ei[e], c = ei[E_ + e];
    float nv = norm[e];
    float4 m = *(const float4*)(B + (size_t)r * 256 + c4);
    float* ap = agg + (size_t)c * CH + c4;
    atomicAdd(ap + 0, nv * m.x);
    atomicAdd(ap + 1, nv * m.y);
    atomicAdd(ap + 2, nv * m.z);
    atomicAdd(ap + 3, nv * m.w);
}

// x_out = relu(agg + v + bias); v = B cols 128..255
__global__ void k_epi(const float* __restrict__ agg, const float* __restrict__ B,
                      const float* __restrict__ bias, float* __restrict__ out0,
                      float* __restrict__ out1) {
    int i = blockIdx.x * 256 + threadIdx.x;     // N_*CH threads
    int n = i >> 7, c = i & 127;
    float v = agg[i] + B[(size_t)n * 256 + CH + c] + bias[c];
    v = fmaxf(v, 0.f);
    out0[i] = v;
    if (out1) out1[i] = v;
}

__device__ inline float bf2f(unsigned int u16) {
    union { unsigned int i; float f; } x; x.i = u16 << 16; return x.f;
}

// pred[e] = mb2 + sum_j relu(P[row][j] + Q[col][j] + mb1[j]) * mw2[j]
// PQ: Nx1024 bf16, P = [0,512), Q = [512,1024). One wave per edge.
__global__ __launch_bounds__(256) void k_edge(const int* __restrict__ ei,
        const __hip_bfloat16* __restrict__ PQ, const float* __restrict__ mb1,
        const float* __restrict__ mw2, const float* __restrict__ mb2,
        float* __restrict__ pred) {
    int wid = threadIdx.x >> 6, lane = threadIdx.x & 63;
    int e = blockIdx.x * 4 + wid;
    int r = ei[e], c = ei[E_ + e];
    const unsigned short* base = (const unsigned short*)PQ;
    uint4 up = *(const uint4*)(base + (size_t)r * 1024 + lane * 8);
    uint4 uq = *(const uint4*)(base + (size_t)c * 1024 + 512 + lane * 8);
    float4 b0 = *(const float4*)(mb1 + lane * 8);
    float4 b1 = *(const float4*)(mb1 + lane * 8 + 4);
    float4 w0 = *(const float4*)(mw2 + lane * 8);
    float4 w1 = *(const float4*)(mw2 + lane * 8 + 4);
    unsigned int pu[4] = {up.x, up.y, up.z, up.w};
    unsigned int qu[4] = {uq.x, uq.y, uq.z, uq.w};
    float bb[8] = {b0.x,b0.y,b0.z,b0.w,b1.x,b1.y,b1.z,b1.w};
    float ww[8] = {w0.x,w0.y,w0.z,w0.w,w1.x,w1.y,w1.z,w1.w};
    float s = 0.f;
    #pragma unroll
    for (int k = 0; k < 4; ++k) {
        float p0 = bf2f(pu[k] & 0xffffu), p1 = bf2f(pu[k] >> 16);
        float q0 = bf2f(qu[k] & 0xffffu), q1 = bf2f(qu[k] >> 16);
        float h0 = fmaxf(p0 + q0 + bb[2*k],     0.f);
        float h1 = fmaxf(p1 + q1 + bb[2*k + 1], 0.f);
        s += h0 * ww[2*k] + h1 * ww[2*k + 1];
    }
    #pragma unroll
    for (int m = 32; m >= 1; m >>= 1) s += __shfl_xor(s, m, 64);
    if (lane == 0) pred[e] = s + mb2[0];
}

// one block per graph: stable bitonic sort (desc by pred, ties by idx asc),
// then write causal/conf gathers + the full pred copy.
__global__ __launch_bounds__(256) void k_sort(const float* __restrict__ pred,
        const int* __restrict__ ei, const float* __restrict__ ea,
        float* __restrict__ out) {
    __shared__ float key[256];
    __shared__ int   idx[256];
    int g = blockIdx.x, t = threadIdx.x;
    int ebase = g * EPG;
    float p = pred[ebase + t];
    key[t] = p; idx[t] = t;
    for (int k2 = 2; k2 <= 256; k2 <<= 1) {
        for (int j = k2 >> 1; j >= 1; j >>= 1) {
            __syncthreads();
            int ixj = t ^ j;
            if (ixj > t) {
                float ka = key[t], kb = key[ixj];
                int   ia = idx[t], ib = idx[ixj];
                bool up = ((t & k2) == 0);
                bool a_before_b = (ka > kb) || (ka == kb && ia < ib);
                bool do_swap = up ? !a_before_b : a_before_b;
                if (do_swap) { key[t] = kb; key[ixj] = ka; idx[t] = ib; idx[ixj] = ia; }
            }
        }
    }
    __syncthreads();
    int el = idx[t];
    int eg = ebase + el;
    float pv = key[t];
    float r = (float)ei[eg];
    float c = (float)ei[E_ + eg];
    float av = ea[eg];
    if (t < KSEL) {
        int oo = g * KSEL + t;
        out[OFF1 + oo]      = r;
        out[OFF1 + GK + oo] = c;
        out[OFF2 + oo]      = av;
        out[OFF3 + oo]      = pv;
    } else {
        int oo = g * KSEL + (t - KSEL);
        out[OFF6 + oo]      = r;
        out[OFF6 + GK + oo] = c;
        out[OFF7 + oo]      = av;
        out[OFF8 + oo]      = -pv;
    }
    out[OFF10 + ebase + t] = p;
}

__global__ void k_batch(const int* __restrict__ batch, float* __restrict__ out) {
    int i = blockIdx.x * 256 + threadIdx.x;
    if (i < N_) { float b = (float)batch[i]; out[OFF4 + i] = b; out[OFF9 + i] = b; }
}

extern "C" void kernel_launch(void* const* d_in, const int* in_sizes, int n_in,
                              void* d_out, int out_size, void* d_ws, size_t ws_size,
                              hipStream_t stream) {
    const float* x     = (const float*)d_in[0];
    const int*   ei    = (const int*)  d_in[1];
    const float* ea    = (const float*)d_in[2];
    const int*   batch = (const int*)  d_in[3];
    const float* W1    = (const float*)d_in[4];
    const float* V1    = (const float*)d_in[5];
    const float* b1    = (const float*)d_in[6];
    const float* W2    = (const float*)d_in[7];
    const float* V2    = (const float*)d_in[8];
    const float* b2    = (const float*)d_in[9];
    const float* mw1   = (const float*)d_in[10];
    const float* mb1   = (const float*)d_in[11];
    const float* mw2   = (const float*)d_in[12];
    const float* mb2   = (const float*)d_in[13];
    float* out = (float*)d_out;

    char* ws = (char*)d_ws;
    size_t o = 0;
    float* deg  = (float*)(ws + o); o += (size_t)N_ * 4;
    float* norm = (float*)(ws + o); o += (size_t)E_ * 4;
    float* WV1  = (float*)(ws + o); o += (size_t)IN_CH * 256 * 4;
    float* WV2  = (float*)(ws + o); o += (size_t)CH * 256 * 4;
    float* Mw   = (float*)(ws + o); o += (size_t)CH * 1024 * 4;
    float* pred = (float*)(ws + o); o += (size_t)E_ * 4;
    char* big = ws + o;                                   // 128 MiB region
    float* B   = (float*)big;                             // N x 256 f32
    float* x1  = (float*)(big + (size_t)N_ * 256 * 4);    // N x 128 f32
    float* agg = (float*)(big + (size_t)N_ * 384 * 4);    // N x 128 f32
    __hip_bfloat16* PQ = (__hip_bfloat16*)big;            // N x 1024 bf16 (aliases all 3, used after)

    // degree / norm
    hipMemsetAsync(deg, 0, (size_t)N_ * 4, stream);
    k_deg <<<E_/256, 256, 0, stream>>>(ei, ea, deg);
    k_dis <<<N_/256, 256, 0, stream>>>(deg);
    k_norm<<<E_/256, 256, 0, stream>>>(ei, ea, deg, norm);
    k_concat<<<768, 256, 0, stream>>>(W1, V1, W2, V2, mw1, WV1, WV2, Mw);

    dim3 g1(N_/64, 256/64);
    // layer 1
    gemm_kernel<false><<<g1, 256, 0, stream>>>(x, WV1, B, N_, 256, IN_CH);
    hipMemsetAsync(agg, 0, (size_t)N_ * CH * 4, stream);
    k_scatter<<<(E_*32)/256, 256, 0, stream>>>(ei, norm, B, agg);
    k_epi<<<(N_*CH)/256, 256, 0, stream>>>(agg, B, b1, x1, nullptr);
    // layer 2 -> x2 written to both OFF0 and OFF5 of d_out
    gemm_kernel<false><<<g1, 256, 0, stream>>>(x1, WV2, B, N_, 256, CH);
    hipMemsetAsync(agg, 0, (size_t)N_ * CH * 4, stream);
    k_scatter<<<(E_*32)/256, 256, 0, stream>>>(ei, norm, B, agg);
    k_epi<<<(N_*CH)/256, 256, 0, stream>>>(agg, B, b2, out + OFF0, out + OFF5);
    // edge MLP hoisted to nodes: PQ = x2 @ Mw (N x 1024), bf16 store
    dim3 g3(N_/64, 1024/64);
    gemm_kernel<true><<<g3, 256, 0, stream>>>(out + OFF0, Mw, PQ, N_, 1024, CH);
    k_edge<<<E_/4, 256, 0, stream>>>(ei, PQ, mb1, mw2, mb2, pred);
    // per-graph top-K partition + outputs
    k_sort<<<G_, 256, 0, stream>>>(pred, ei, ea, out);
    k_batch<<<N_/256, 256, 0, stream>>>(batch, out);
}

// Round 2
// 1194.916 us; speedup vs baseline: 1.5518x; 1.5518x over previous
//
#include <hip/hip_runtime.h>
#include <hip/hip_bf16.h>
#include <stdint.h>

#define G_    1024
#define NPG   64
#define EPG   256
#define N_    (G_*NPG)     // 65536
#define E_    (G_*EPG)     // 262144
#define IN_CH 768
#define CH    128
#define KSEL  128
#define HID   512          // 4*CH

// ---- output layout (element offsets, all float32) ----
#define NCH  (N_*CH)       // 8388608
#define GK   (G_*KSEL)     // 131072
#define OFF0 0
#define OFF1 (OFF0 + NCH)
#define OFF2 (OFF1 + 2*GK)
#define OFF3 (OFF2 + GK)
#define OFF4 (OFF3 + GK)
#define OFF5 (OFF4 + N_)
#define OFF6 (OFF5 + NCH)
#define OFF7 (OFF6 + 2*GK)
#define OFF8 (OFF7 + GK)
#define OFF9 (OFF8 + GK)
#define OFF10 (OFF9 + N_)

typedef unsigned short u16;
typedef unsigned int   u32;
typedef __attribute__((ext_vector_type(8))) short bf16x8;
typedef __attribute__((ext_vector_type(4))) float f32x4;

__device__ __forceinline__ u16 f2bf(float x) {
    union { float f; u32 u; } v; v.f = x;
    u32 r = v.u + 0x7fffu + ((v.u >> 16) & 1u);   // RNE
    return (u16)(r >> 16);
}
__device__ __forceinline__ float bf2f(u32 h) {
    union { u32 u; float f; } v; v.u = h << 16; return v.f;
}

__global__ void k_deg(const int* __restrict__ ei, const float* __restrict__ ea,
                      float* __restrict__ deg) {
    int e = blockIdx.x * 256 + threadIdx.x;
    if (e < E_) atomicAdd(&deg[ei[E_ + e]], ea[e]);
}

__global__ void k_dis(float* __restrict__ deg) {
    int i = blockIdx.x * 256 + threadIdx.x;
    if (i < N_) { float d = deg[i]; deg[i] = d > 0.f ? 1.0f / sqrtf(d) : 0.f; }
}

__global__ void k_norm(const int* __restrict__ ei, const float* __restrict__ ea,
                       const float* __restrict__ dis, float* __restrict__ norm) {
    int e = blockIdx.x * 256 + threadIdx.x;
    if (e < E_) norm[e] = dis[ei[e]] * ea[e] * dis[ei[E_ + e]];
}

// Build TRANSPOSED bf16 weights:
//  WV1t (256x768): row c holds col c of [W1|V1]
//  WV2t (256x128): row c holds col c of [W2|V2]
//  Mwt (1024x128): row c, c<512 -> mw1[:,c] rows 0..127 ; c>=512 -> mw1 rows 128..255 col c-512
__global__ void k_concat(const float* __restrict__ W1, const float* __restrict__ V1,
                         const float* __restrict__ W2, const float* __restrict__ V2,
                         const float* __restrict__ mw1,
                         u16* __restrict__ WV1t, u16* __restrict__ WV2t,
                         u16* __restrict__ Mwt) {
    int i = blockIdx.x * 256 + threadIdx.x;
    if (i < 256 * IN_CH) {
        int c = i / IN_CH, r = i - c * IN_CH;
        WV1t[i] = f2bf(c < CH ? W1[r*CH + c] : V1[r*CH + (c - CH)]);
    }
    if (i < 256 * CH) {
        int c = i >> 7, r = i & 127;
        WV2t[i] = f2bf(c < CH ? W2[r*CH + c] : V2[r*CH + (c - CH)]);
    }
    if (i < 1024 * CH) {
        int c = i >> 7, r = i & 127;
        Mwt[i] = f2bf(c < HID ? mw1[r*HID + c] : mw1[(CH + r)*HID + (c - HID)]);
    }
}

// bf16 MFMA GEMM: C(MxN) = A(MxK) @ Bt(NxK)^T.  Tile 128x128, BK=32, 256 thr = 4 waves.
// LDS tiles [128][32] bf16 with granule swizzle c16 ^= (row&3) -> <=2-way bank conflicts.
template<int A_F32, int C_BF16>
__global__ __launch_bounds__(256) void mfma_gemm(const void* __restrict__ Ap,
        const u16* __restrict__ Bt, void* __restrict__ Cp, int Nn, int K) {
    __shared__ u16 As[128 * 32];
    __shared__ u16 Bs[128 * 32];
    const int t = threadIdx.x;
    const int lane = t & 63, w = t >> 6;
    const int wr = (w >> 1) << 6, wc = (w & 1) << 6;
    const size_t bm = (size_t)blockIdx.x * 128;
    const size_t bn = (size_t)blockIdx.y * 128;
    const int r16 = lane & 15, kq = lane >> 4;
    f32x4 acc[4][4];
    #pragma unroll
    for (int m = 0; m < 4; ++m)
        #pragma unroll
        for (int n = 0; n < 4; ++n)
            acc[m][n] = (f32x4){0.f, 0.f, 0.f, 0.f};

    for (int k0 = 0; k0 < K; k0 += 32) {
        #pragma unroll
        for (int i = 0; i < 2; ++i) {
            int g = t + i * 256;            // granule: 16B of a row
            int row = g >> 2, c16 = g & 3;
            int sc = c16 ^ (row & 3);       // swizzled granule slot
            uint4 va;
            if (A_F32) {
                const float* ap = (const float*)Ap + (bm + row) * (size_t)K + k0 + c16 * 8;
                float4 lo = *(const float4*)ap;
                float4 hi = *(const float4*)(ap + 4);
                union { uint4 q; u16 s[8]; } pk;
                pk.s[0]=f2bf(lo.x); pk.s[1]=f2bf(lo.y); pk.s[2]=f2bf(lo.z); pk.s[3]=f2bf(lo.w);
                pk.s[4]=f2bf(hi.x); pk.s[5]=f2bf(hi.y); pk.s[6]=f2bf(hi.z); pk.s[7]=f2bf(hi.w);
                va = pk.q;
            } else {
                va = *(const uint4*)((const u16*)Ap + (bm + row) * (size_t)K + k0 + c16 * 8);
            }
            *(uint4*)&As[row * 32 + sc * 8] = va;
            uint4 vb = *(const uint4*)(Bt + (bn + row) * (size_t)K + k0 + c16 * 8);
            *(uint4*)&Bs[row * 32 + sc * 8] = vb;
        }
        __syncthreads();
        bf16x8 a[4], b[4];
        #pragma unroll
        for (int m = 0; m < 4; ++m) {
            int row = wr + m * 16 + r16;
            a[m] = *(const bf16x8*)&As[row * 32 + ((kq ^ (row & 3)) * 8)];
        }
        #pragma unroll
        for (int n = 0; n < 4; ++n) {
            int row = wc + n * 16 + r16;
            b[n] = *(const bf16x8*)&Bs[row * 32 + ((kq ^ (row & 3)) * 8)];
        }
        #pragma unroll
        for (int m = 0; m < 4; ++m)
            #pragma unroll
            for (int n = 0; n < 4; ++n)
                acc[m][n] = __builtin_amdgcn_mfma_f32_16x16x32_bf16(a[m], b[n], acc[m][n], 0, 0, 0);
        __syncthreads();
    }
    // C/D layout: col = lane&15, row = (lane>>4)*4 + reg
    #pragma unroll
    for (int m = 0; m < 4; ++m) {
        #pragma unroll
        for (int j = 0; j < 4; ++j) {
            size_t row = bm + wr + m * 16 + kq * 4 + j;
            #pragma unroll
            for (int n = 0; n < 4; ++n) {
                size_t col = bn + wc + n * 16 + r16;
                if (C_BF16) ((u16*)Cp)[row * Nn + col] = f2bf(acc[m][n][j]);
                else        ((float*)Cp)[row * Nn + col] = acc[m][n][j];
            }
        }
    }
}

// agg[col] += norm * m[row];  B holds [m|v] (Nx256 f32), m = cols 0..127
__global__ void k_scatter(const int* __restrict__ ei, const float* __restrict__ norm,
                          const float* __restrict__ B, float* __restrict__ agg) {
    int gid = blockIdx.x * 256 + threadIdx.x;   // E_*32 threads
    int e  = gid >> 5;
    int c4 = (gid & 31) << 2;
    if (e >= E_) return;
    int r = ei[e], c = ei[E_ + e];
    float nv = norm[e];
    float4 m = *(const float4*)(B + (size_t)r * 256 + c4);
    float* ap = agg + (size_t)c * CH + c4;
    atomicAdd(ap + 0, nv * m.x);
    atomicAdd(ap + 1, nv * m.y);
    atomicAdd(ap + 2, nv * m.z);
    atomicAdd(ap + 3, nv * m.w);
}

// layer-1 epilogue: x1b = bf16(relu(agg + v + bias))
__global__ void k_epi1(const float* __restrict__ agg, const float* __restrict__ B,
                       const float* __restrict__ bias, u16* __restrict__ x1b) {
    int i = blockIdx.x * 256 + threadIdx.x;     // N_*CH/4 threads
    int n = i >> 5, c4 = (i & 31) << 2;
    float4 a = *(const float4*)(agg + (size_t)n * CH + c4);
    float4 v = *(const float4*)(B + (size_t)n * 256 + CH + c4);
    float4 bs = *(const float4*)(bias + c4);
    union { uint2 d; u16 s[4]; } p;
    p.s[0] = f2bf(fmaxf(a.x + v.x + bs.x, 0.f));
    p.s[1] = f2bf(fmaxf(a.y + v.y + bs.y, 0.f));
    p.s[2] = f2bf(fmaxf(a.z + v.z + bs.z, 0.f));
    p.s[3] = f2bf(fmaxf(a.w + v.w + bs.w, 0.f));
    *(uint2*)(x1b + (size_t)n * CH + c4) = p.d;
}

// layer-2 epilogue: x2 (f32) to both output slots + bf16 copy for GEMM3
__global__ void k_epi2(const float* __restrict__ agg, const float* __restrict__ B,
                       const float* __restrict__ bias, float* __restrict__ out0,
                       float* __restrict__ out5, u16* __restrict__ x2b) {
    int i = blockIdx.x * 256 + threadIdx.x;     // N_*CH/4 threads
    int n = i >> 5, c4 = (i & 31) << 2;
    float4 a = *(const float4*)(agg + (size_t)n * CH + c4);
    float4 v = *(const float4*)(B + (size_t)n * 256 + CH + c4);
    float4 bs = *(const float4*)(bias + c4);
    float4 r;
    r.x = fmaxf(a.x + v.x + bs.x, 0.f);
    r.y = fmaxf(a.y + v.y + bs.y, 0.f);
    r.z = fmaxf(a.z + v.z + bs.z, 0.f);
    r.w = fmaxf(a.w + v.w + bs.w, 0.f);
    size_t off = (size_t)n * CH + c4;
    *(float4*)(out0 + off) = r;
    *(float4*)(out5 + off) = r;
    union { uint2 d; u16 s[4]; } p;
    p.s[0] = f2bf(r.x); p.s[1] = f2bf(r.y); p.s[2] = f2bf(r.z); p.s[3] = f2bf(r.w);
    *(uint2*)(x2b + off) = p.d;
}

// pred[e] = mb2 + sum_j relu(P[row][j] + Q[col][j] + mb1[j]) * mw2[j]
// PQ: Nx1024 bf16, P = [0,512), Q = [512,1024). One wave per edge.
__global__ __launch_bounds__(256) void k_edge(const int* __restrict__ ei,
        const u16* __restrict__ PQ, const float* __restrict__ mb1,
        const float* __restrict__ mw2, const float* __restrict__ mb2,
        float* __restrict__ pred) {
    int wid = threadIdx.x >> 6, lane = threadIdx.x & 63;
    int e = blockIdx.x * 4 + wid;
    int r = ei[e], c = ei[E_ + e];
    uint4 up = *(const uint4*)(PQ + (size_t)r * 1024 + lane * 8);
    uint4 uq = *(const uint4*)(PQ + (size_t)c * 1024 + 512 + lane * 8);
    float4 b0 = *(const float4*)(mb1 + lane * 8);
    float4 b1 = *(const float4*)(mb1 + lane * 8 + 4);
    float4 w0 = *(const float4*)(mw2 + lane * 8);
    float4 w1 = *(const float4*)(mw2 + lane * 8 + 4);
    u32 pu[4] = {up.x, up.y, up.z, up.w};
    u32 qu[4] = {uq.x, uq.y, uq.z, uq.w};
    float bb[8] = {b0.x,b0.y,b0.z,b0.w,b1.x,b1.y,b1.z,b1.w};
    float ww[8] = {w0.x,w0.y,w0.z,w0.w,w1.x,w1.y,w1.z,w1.w};
    float s = 0.f;
    #pragma unroll
    for (int k = 0; k < 4; ++k) {
        float p0 = bf2f(pu[k] & 0xffffu), p1 = bf2f(pu[k] >> 16);
        float q0 = bf2f(qu[k] & 0xffffu), q1 = bf2f(qu[k] >> 16);
        float h0 = fmaxf(p0 + q0 + bb[2*k],     0.f);
        float h1 = fmaxf(p1 + q1 + bb[2*k + 1], 0.f);
        s += h0 * ww[2*k] + h1 * ww[2*k + 1];
    }
    #pragma unroll
    for (int m = 32; m >= 1; m >>= 1) s += __shfl_xor(s, m, 64);
    if (lane == 0) pred[e] = s + mb2[0];
}

// one block per graph: stable bitonic sort (desc by pred, ties by idx asc),
// then write causal/conf gathers + the full pred copy.
__global__ __launch_bounds__(256) void k_sort(const float* __restrict__ pred,
        const int* __restrict__ ei, const float* __restrict__ ea,
        float* __restrict__ out) {
    __shared__ float key[256];
    __shared__ int   idx[256];
    int g = blockIdx.x, t = threadIdx.x;
    int ebase = g * EPG;
    float p = pred[ebase + t];
    key[t] = p; idx[t] = t;
    for (int k2 = 2; k2 <= 256; k2 <<= 1) {
        for (int j = k2 >> 1; j >= 1; j >>= 1) {
            __syncthreads();
            int ixj = t ^ j;
            if (ixj > t) {
                float ka = key[t], kb = key[ixj];
                int   ia = idx[t], ib = idx[ixj];
                bool up = ((t & k2) == 0);
                bool a_before_b = (ka > kb) || (ka == kb && ia < ib);
                bool do_swap = up ? !a_before_b : a_before_b;
                if (do_swap) { key[t] = kb; key[ixj] = ka; idx[t] = ib; idx[ixj] = ia; }
            }
        }
    }
    __syncthreads();
    int el = idx[t];
    int eg = ebase + el;
    float pv = key[t];
    float r = (float)ei[eg];
    float c = (float)ei[E_ + eg];
    float av = ea[eg];
    if (t < KSEL) {
        int oo = g * KSEL + t;
        out[OFF1 + oo]      = r;
        out[OFF1 + GK + oo] = c;
        out[OFF2 + oo]      = av;
        out[OFF3 + oo]      = pv;
    } else {
        int oo = g * KSEL + (t - KSEL);
        out[OFF6 + oo]      = r;
        out[OFF6 + GK + oo] = c;
        out[OFF7 + oo]      = av;
        out[OFF8 + oo]      = -pv;
    }
    out[OFF10 + ebase + t] = p;
}

__global__ void k_batch(const int* __restrict__ batch, float* __restrict__ out) {
    int i = blockIdx.x * 256 + threadIdx.x;
    if (i < N_) { float b = (float)batch[i]; out[OFF4 + i] = b; out[OFF9 + i] = b; }
}

extern "C" void kernel_launch(void* const* d_in, const int* in_sizes, int n_in,
                              void* d_out, int out_size, void* d_ws, size_t ws_size,
                              hipStream_t stream) {
    const float* x     = (const float*)d_in[0];
    const int*   ei    = (const int*)  d_in[1];
    const float* ea    = (const float*)d_in[2];
    const int*   batch = (const int*)  d_in[3];
    const float* W1    = (const float*)d_in[4];
    const float* V1    = (const float*)d_in[5];
    const float* b1    = (const float*)d_in[6];
    const float* W2    = (const float*)d_in[7];
    const float* V2    = (const float*)d_in[8];
    const float* b2    = (const float*)d_in[9];
    const float* mw1   = (const float*)d_in[10];
    const float* mb1   = (const float*)d_in[11];
    const float* mw2   = (const float*)d_in[12];
    const float* mb2   = (const float*)d_in[13];
    float* out = (float*)d_out;

    char* ws = (char*)d_ws;
    size_t o = 0;
    float* deg  = (float*)(ws + o); o += (size_t)N_ * 4;          // 256 KB
    float* norm = (float*)(ws + o); o += (size_t)E_ * 4;          // 1 MB
    float* pred = (float*)(ws + o); o += (size_t)E_ * 4;          // 1 MB
    u16* WV1t   = (u16*)(ws + o);   o += (size_t)256 * IN_CH * 2; // 384 KB
    u16* WV2t   = (u16*)(ws + o);   o += (size_t)256 * CH * 2;    // 64 KB
    u16* Mwt    = (u16*)(ws + o);   o += (size_t)1024 * CH * 2;   // 256 KB
    u16* x2b    = (u16*)(ws + o);   o += (size_t)N_ * CH * 2;     // 16 MB
    char* pqb   = ws + o;                                         // PQ region start
    u16* x1b    = (u16*)(ws + o);   o += (size_t)N_ * CH * 2;     // 16 MB
    float* agg  = (float*)(ws + o); o += (size_t)N_ * CH * 4;     // 32 MB
    float* B    = (float*)(ws + o); o += (size_t)N_ * 256 * 4;    // 64 MB
    o += (size_t)16 << 20;                                        // pad so PQ fits
    u16* PQ = (u16*)pqb;   // N x 1024 bf16 = 128 MB, aliases x1b/agg/B/pad (all dead at GEMM3)

    // degree / norm / weights
    hipMemsetAsync(deg, 0, (size_t)N_ * 4, stream);
    k_deg <<<E_/256, 256, 0, stream>>>(ei, ea, deg);
    k_dis <<<N_/256, 256, 0, stream>>>(deg);
    k_norm<<<E_/256, 256, 0, stream>>>(ei, ea, deg, norm);
    k_concat<<<768, 256, 0, stream>>>(W1, V1, W2, V2, mw1, WV1t, WV2t, Mwt);

    dim3 g1(N_/128, 256/128);
    // layer 1: B = [m|v] = x @ [W1|V1]  (A fp32 converted in staging)
    mfma_gemm<1,0><<<g1, 256, 0, stream>>>(x, WV1t, B, 256, IN_CH);
    hipMemsetAsync(agg, 0, (size_t)N_ * CH * 4, stream);
    k_scatter<<<(E_*32)/256, 256, 0, stream>>>(ei, norm, B, agg);
    k_epi1<<<(N_*CH/4)/256, 256, 0, stream>>>(agg, B, b1, x1b);
    // layer 2
    mfma_gemm<0,0><<<g1, 256, 0, stream>>>(x1b, WV2t, B, 256, CH);
    hipMemsetAsync(agg, 0, (size_t)N_ * CH * 4, stream);
    k_scatter<<<(E_*32)/256, 256, 0, stream>>>(ei, norm, B, agg);
    k_epi2<<<(N_*CH/4)/256, 256, 0, stream>>>(agg, B, b2, out + OFF0, out + OFF5, x2b);
    // edge MLP hoisted to nodes: PQ = x2 @ Mw (N x 1024), bf16 out
    dim3 g3(N_/128, 1024/128);
    mfma_gemm<0,1><<<g3, 256, 0, stream>>>(x2b, Mwt, PQ, 1024, CH);
    k_edge<<<E_/4, 256, 0, stream>>>(ei, PQ, mb1, mw2, mb2, pred);
    // per-graph top-K partition + outputs
    k_sort<<<G_, 256, 0, stream>>>(pred, ei, ea, out);
    k_batch<<<N_/256, 256, 0, stream>>>(batch, out);
}

// Round 3
// 312.779 us; speedup vs baseline: 5.9284x; 3.8203x over previous
//
#include <hip/hip_runtime.h>
#include <hip/hip_bf16.h>
#include <stdint.h>

#define G_    1024
#define NPG   64
#define EPG   256
#define N_    (G_*NPG)     // 65536
#define E_    (G_*EPG)     // 262144
#define IN_CH 768
#define CH    128
#define KSEL  128
#define HID   512          // 4*CH

// ---- output layout (element offsets, all float32) ----
#define NCH  (N_*CH)       // 8388608
#define GK   (G_*KSEL)     // 131072
#define OFF0 0
#define OFF1 (OFF0 + NCH)
#define OFF2 (OFF1 + 2*GK)
#define OFF3 (OFF2 + GK)
#define OFF4 (OFF3 + GK)
#define OFF5 (OFF4 + N_)
#define OFF6 (OFF5 + NCH)
#define OFF7 (OFF6 + 2*GK)
#define OFF8 (OFF7 + GK)
#define OFF9 (OFF8 + GK)
#define OFF10 (OFF9 + N_)

typedef unsigned short u16;
typedef unsigned int   u32;
typedef __attribute__((ext_vector_type(8))) short bf16x8;
typedef __attribute__((ext_vector_type(4))) float f32x4;

__device__ __forceinline__ u16 f2bf(float x) {
    union { float f; u32 u; } v; v.f = x;
    u32 r = v.u + 0x7fffu + ((v.u >> 16) & 1u);   // RNE
    return (u16)(r >> 16);
}
__device__ __forceinline__ float bf2f(u32 h) {
    union { u32 u; float f; } v; v.u = h << 16; return v.f;
}

__global__ void k_deg(const int* __restrict__ ei, const float* __restrict__ ea,
                      float* __restrict__ deg) {
    int e = blockIdx.x * 256 + threadIdx.x;
    if (e < E_) atomicAdd(&deg[ei[E_ + e]], ea[e]);
}

__global__ void k_dis(float* __restrict__ deg) {
    int i = blockIdx.x * 256 + threadIdx.x;
    if (i < N_) { float d = deg[i]; deg[i] = d > 0.f ? 1.0f / sqrtf(d) : 0.f; }
}

__global__ void k_norm(const int* __restrict__ ei, const float* __restrict__ ea,
                       const float* __restrict__ dis, float* __restrict__ norm) {
    int e = blockIdx.x * 256 + threadIdx.x;
    if (e < E_) norm[e] = dis[ei[e]] * ea[e] * dis[ei[E_ + e]];
}

// Build TRANSPOSED bf16 weights:
//  WV1t (256x768): row c holds col c of [W1|V1]
//  WV2t (256x128): row c holds col c of [W2|V2]
//  Mwt (1024x128): row c, c<512 -> mw1[:,c] rows 0..127 ; c>=512 -> mw1 rows 128..255 col c-512
__global__ void k_concat(const float* __restrict__ W1, const float* __restrict__ V1,
                         const float* __restrict__ W2, const float* __restrict__ V2,
                         const float* __restrict__ mw1,
                         u16* __restrict__ WV1t, u16* __restrict__ WV2t,
                         u16* __restrict__ Mwt) {
    int i = blockIdx.x * 256 + threadIdx.x;
    if (i < 256 * IN_CH) {
        int c = i / IN_CH, r = i - c * IN_CH;
        WV1t[i] = f2bf(c < CH ? W1[r*CH + c] : V1[r*CH + (c - CH)]);
    }
    if (i < 256 * CH) {
        int c = i >> 7, r = i & 127;
        WV2t[i] = f2bf(c < CH ? W2[r*CH + c] : V2[r*CH + (c - CH)]);
    }
    if (i < 1024 * CH) {
        int c = i >> 7, r = i & 127;
        Mwt[i] = f2bf(c < HID ? mw1[r*HID + c] : mw1[(CH + r)*HID + (c - HID)]);
    }
}

// bf16 MFMA GEMM: C(MxN) = A(MxK) @ Bt(NxK)^T.  Tile 128x128, BK=32, 256 thr = 4 waves.
template<int A_F32, int C_BF16>
__global__ __launch_bounds__(256) void mfma_gemm(const void* __restrict__ Ap,
        const u16* __restrict__ Bt, void* __restrict__ Cp, int Nn, int K) {
    __shared__ u16 As[128 * 32];
    __shared__ u16 Bs[128 * 32];
    const int t = threadIdx.x;
    const int lane = t & 63, w = t >> 6;
    const int wr = (w >> 1) << 6, wc = (w & 1) << 6;
    const size_t bm = (size_t)blockIdx.x * 128;
    const size_t bn = (size_t)blockIdx.y * 128;
    const int r16 = lane & 15, kq = lane >> 4;
    f32x4 acc[4][4];
    #pragma unroll
    for (int m = 0; m < 4; ++m)
        #pragma unroll
        for (int n = 0; n < 4; ++n)
            acc[m][n] = (f32x4){0.f, 0.f, 0.f, 0.f};

    for (int k0 = 0; k0 < K; k0 += 32) {
        #pragma unroll
        for (int i = 0; i < 2; ++i) {
            int g = t + i * 256;            // granule: 16B of a row
            int row = g >> 2, c16 = g & 3;
            int sc = c16 ^ (row & 3);       // swizzled granule slot
            uint4 va;
            if (A_F32) {
                const float* ap = (const float*)Ap + (bm + row) * (size_t)K + k0 + c16 * 8;
                float4 lo = *(const float4*)ap;
                float4 hi = *(const float4*)(ap + 4);
                union { uint4 q; u16 s[8]; } pk;
                pk.s[0]=f2bf(lo.x); pk.s[1]=f2bf(lo.y); pk.s[2]=f2bf(lo.z); pk.s[3]=f2bf(lo.w);
                pk.s[4]=f2bf(hi.x); pk.s[5]=f2bf(hi.y); pk.s[6]=f2bf(hi.z); pk.s[7]=f2bf(hi.w);
                va = pk.q;
            } else {
                va = *(const uint4*)((const u16*)Ap + (bm + row) * (size_t)K + k0 + c16 * 8);
            }
            *(uint4*)&As[row * 32 + sc * 8] = va;
            uint4 vb = *(const uint4*)(Bt + (bn + row) * (size_t)K + k0 + c16 * 8);
            *(uint4*)&Bs[row * 32 + sc * 8] = vb;
        }
        __syncthreads();
        bf16x8 a[4], b[4];
        #pragma unroll
        for (int m = 0; m < 4; ++m) {
            int row = wr + m * 16 + r16;
            a[m] = *(const bf16x8*)&As[row * 32 + ((kq ^ (row & 3)) * 8)];
        }
        #pragma unroll
        for (int n = 0; n < 4; ++n) {
            int row = wc + n * 16 + r16;
            b[n] = *(const bf16x8*)&Bs[row * 32 + ((kq ^ (row & 3)) * 8)];
        }
        #pragma unroll
        for (int m = 0; m < 4; ++m)
            #pragma unroll
            for (int n = 0; n < 4; ++n)
                acc[m][n] = __builtin_amdgcn_mfma_f32_16x16x32_bf16(a[m], b[n], acc[m][n], 0, 0, 0);
        __syncthreads();
    }
    // C/D layout: col = lane&15, row = (lane>>4)*4 + reg
    #pragma unroll
    for (int m = 0; m < 4; ++m) {
        #pragma unroll
        for (int j = 0; j < 4; ++j) {
            size_t row = bm + wr + m * 16 + kq * 4 + j;
            #pragma unroll
            for (int n = 0; n < 4; ++n) {
                size_t col = bn + wc + n * 16 + r16;
                if (C_BF16) ((u16*)Cp)[row * Nn + col] = f2bf(acc[m][n][j]);
                else        ((float*)Cp)[row * Nn + col] = acc[m][n][j];
            }
        }
    }
}

// Fused per-graph aggregation + epilogue.
// agg[c][ch] = sum_r A[r][c] * m[r][ch], via dense 64x64 LDS adjacency + MFMA.
// Then out = relu(agg + v + bias).  B holds [m|v] (N x 256 f32).
template<int LAYER>
__global__ __launch_bounds__(256) void k_agg(const int* __restrict__ ei,
        const float* __restrict__ norm, const float* __restrict__ B,
        const float* __restrict__ bias, float* __restrict__ out0,
        float* __restrict__ out5, u16* __restrict__ xb) {
    __shared__ float A_s[64 * 65];   // [r][c], padded
    __shared__ u16   Ms[64 * 132];   // m bf16 [r][ch], padded
    const int g = blockIdx.x, t = threadIdx.x;
    const int lane = t & 63, w = t >> 6;
    const int r16 = lane & 15, kq = lane >> 4;
    const size_t nbase = (size_t)g * 64;

    #pragma unroll
    for (int i = t; i < 64 * 65; i += 256) A_s[i] = 0.f;
    #pragma unroll
    for (int i = t; i < 64 * 32; i += 256) {
        int row = i >> 5, c4 = (i & 31) << 2;
        float4 mv = *(const float4*)(B + (nbase + row) * 256 + c4);
        union { uint2 d; u16 s[4]; } p;
        p.s[0] = f2bf(mv.x); p.s[1] = f2bf(mv.y);
        p.s[2] = f2bf(mv.z); p.s[3] = f2bf(mv.w);
        *(uint2*)&Ms[row * 132 + c4] = p.d;
    }
    __syncthreads();
    {   // scatter 256 edges into A_s[r][c] (duplicates possible -> atomic)
        int e = g * 256 + t;
        int r = ei[e] & 63, c = ei[E_ + e] & 63;
        atomicAdd(&A_s[r * 65 + c], norm[e]);
    }
    __syncthreads();

    const int n0 = w * 32;           // wave's ch chunk
    f32x4 acc[4][2];
    #pragma unroll
    for (int mt = 0; mt < 4; ++mt)
        #pragma unroll
        for (int nt = 0; nt < 2; ++nt)
            acc[mt][nt] = (f32x4){0.f, 0.f, 0.f, 0.f};

    union bfr { bf16x8 v; u16 s[8]; };
    #pragma unroll
    for (int ks = 0; ks < 2; ++ks) {
        bfr a[4], b[2];
        #pragma unroll
        for (int mt = 0; mt < 4; ++mt)
            #pragma unroll
            for (int i = 0; i < 8; ++i)
                a[mt].s[i] = f2bf(A_s[(ks*32 + kq*8 + i) * 65 + mt*16 + r16]);
        #pragma unroll
        for (int nt = 0; nt < 2; ++nt)
            #pragma unroll
            for (int i = 0; i < 8; ++i)
                b[nt].s[i] = Ms[(ks*32 + kq*8 + i) * 132 + n0 + nt*16 + r16];
        #pragma unroll
        for (int mt = 0; mt < 4; ++mt)
            #pragma unroll
            for (int nt = 0; nt < 2; ++nt)
                acc[mt][nt] = __builtin_amdgcn_mfma_f32_16x16x32_bf16(a[mt].v, b[nt].v, acc[mt][nt], 0, 0, 0);
    }
    // epilogue: C row = output node (c), col = ch
    #pragma unroll
    for (int mt = 0; mt < 4; ++mt) {
        #pragma unroll
        for (int j = 0; j < 4; ++j) {
            int c = mt * 16 + kq * 4 + j;
            size_t node = nbase + c;
            #pragma unroll
            for (int nt = 0; nt < 2; ++nt) {
                int ch = n0 + nt * 16 + r16;
                float v = B[node * 256 + 128 + ch] + bias[ch];
                float r = fmaxf(acc[mt][nt][j] + v, 0.f);
                if (LAYER == 1) {
                    xb[node * 128 + ch] = f2bf(r);
                } else {
                    out0[node * 128 + ch] = r;
                    out5[node * 128 + ch] = r;
                    xb[node * 128 + ch] = f2bf(r);
                }
            }
        }
    }
}

// pred[e] = mb2 + sum_j relu(P[row][j] + Q[col][j] + mb1[j]) * mw2[j]
// PQ: Nx1024 bf16, P = [0,512), Q = [512,1024). One wave per edge.
__global__ __launch_bounds__(256) void k_edge(const int* __restrict__ ei,
        const u16* __restrict__ PQ, const float* __restrict__ mb1,
        const float* __restrict__ mw2, const float* __restrict__ mb2,
        float* __restrict__ pred) {
    int wid = threadIdx.x >> 6, lane = threadIdx.x & 63;
    int e = blockIdx.x * 4 + wid;
    int r = ei[e], c = ei[E_ + e];
    uint4 up = *(const uint4*)(PQ + (size_t)r * 1024 + lane * 8);
    uint4 uq = *(const uint4*)(PQ + (size_t)c * 1024 + 512 + lane * 8);
    float4 b0 = *(const float4*)(mb1 + lane * 8);
    float4 b1 = *(const float4*)(mb1 + lane * 8 + 4);
    float4 w0 = *(const float4*)(mw2 + lane * 8);
    float4 w1 = *(const float4*)(mw2 + lane * 8 + 4);
    u32 pu[4] = {up.x, up.y, up.z, up.w};
    u32 qu[4] = {uq.x, uq.y, uq.z, uq.w};
    float bb[8] = {b0.x,b0.y,b0.z,b0.w,b1.x,b1.y,b1.z,b1.w};
    float ww[8] = {w0.x,w0.y,w0.z,w0.w,w1.x,w1.y,w1.z,w1.w};
    float s = 0.f;
    #pragma unroll
    for (int k = 0; k < 4; ++k) {
        float p0 = bf2f(pu[k] & 0xffffu), p1 = bf2f(pu[k] >> 16);
        float q0 = bf2f(qu[k] & 0xffffu), q1 = bf2f(qu[k] >> 16);
        float h0 = fmaxf(p0 + q0 + bb[2*k],     0.f);
        float h1 = fmaxf(p1 + q1 + bb[2*k + 1], 0.f);
        s += h0 * ww[2*k] + h1 * ww[2*k + 1];
    }
    #pragma unroll
    for (int m = 32; m >= 1; m >>= 1) s += __shfl_xor(s, m, 64);
    if (lane == 0) pred[e] = s + mb2[0];
}

// one block per graph: stable bitonic sort (desc by pred, ties by idx asc),
// then write causal/conf gathers + the full pred copy.
__global__ __launch_bounds__(256) void k_sort(const float* __restrict__ pred,
        const int* __restrict__ ei, const float* __restrict__ ea,
        float* __restrict__ out) {
    __shared__ float key[256];
    __shared__ int   idx[256];
    int g = blockIdx.x, t = threadIdx.x;
    int ebase = g * EPG;
    float p = pred[ebase + t];
    key[t] = p; idx[t] = t;
    for (int k2 = 2; k2 <= 256; k2 <<= 1) {
        for (int j = k2 >> 1; j >= 1; j >>= 1) {
            __syncthreads();
            int ixj = t ^ j;
            if (ixj > t) {
                float ka = key[t], kb = key[ixj];
                int   ia = idx[t], ib = idx[ixj];
                bool up = ((t & k2) == 0);
                bool a_before_b = (ka > kb) || (ka == kb && ia < ib);
                bool do_swap = up ? !a_before_b : a_before_b;
                if (do_swap) { key[t] = kb; key[ixj] = ka; idx[t] = ib; idx[ixj] = ia; }
            }
        }
    }
    __syncthreads();
    int el = idx[t];
    int eg = ebase + el;
    float pv = key[t];
    float r = (float)ei[eg];
    float c = (float)ei[E_ + eg];
    float av = ea[eg];
    if (t < KSEL) {
        int oo = g * KSEL + t;
        out[OFF1 + oo]      = r;
        out[OFF1 + GK + oo] = c;
        out[OFF2 + oo]      = av;
        out[OFF3 + oo]      = pv;
    } else {
        int oo = g * KSEL + (t - KSEL);
        out[OFF6 + oo]      = r;
        out[OFF6 + GK + oo] = c;
        out[OFF7 + oo]      = av;
        out[OFF8 + oo]      = -pv;
    }
    out[OFF10 + ebase + t] = p;
}

__global__ void k_batch(const int* __restrict__ batch, float* __restrict__ out) {
    int i = blockIdx.x * 256 + threadIdx.x;
    if (i < N_) { float b = (float)batch[i]; out[OFF4 + i] = b; out[OFF9 + i] = b; }
}

extern "C" void kernel_launch(void* const* d_in, const int* in_sizes, int n_in,
                              void* d_out, int out_size, void* d_ws, size_t ws_size,
                              hipStream_t stream) {
    const float* x     = (const float*)d_in[0];
    const int*   ei    = (const int*)  d_in[1];
    const float* ea    = (const float*)d_in[2];
    const int*   batch = (const int*)  d_in[3];
    const float* W1    = (const float*)d_in[4];
    const float* V1    = (const float*)d_in[5];
    const float* b1    = (const float*)d_in[6];
    const float* W2    = (const float*)d_in[7];
    const float* V2    = (const float*)d_in[8];
    const float* b2    = (const float*)d_in[9];
    const float* mw1   = (const float*)d_in[10];
    const float* mb1   = (const float*)d_in[11];
    const float* mw2   = (const float*)d_in[12];
    const float* mb2   = (const float*)d_in[13];
    float* out = (float*)d_out;

    char* ws = (char*)d_ws;
    size_t o = 0;
    float* deg  = (float*)(ws + o); o += (size_t)N_ * 4;          // 256 KB
    float* norm = (float*)(ws + o); o += (size_t)E_ * 4;          // 1 MB
    float* pred = (float*)(ws + o); o += (size_t)E_ * 4;          // 1 MB
    u16* WV1t   = (u16*)(ws + o);   o += (size_t)256 * IN_CH * 2; // 384 KB
    u16* WV2t   = (u16*)(ws + o);   o += (size_t)256 * CH * 2;    // 64 KB
    u16* Mwt    = (u16*)(ws + o);   o += (size_t)1024 * CH * 2;   // 256 KB
    u16* x2b    = (u16*)(ws + o);   o += (size_t)N_ * CH * 2;     // 16 MB
    char* pqb   = ws + o;                                         // PQ region start
    u16* x1b    = (u16*)(ws + o);   o += (size_t)N_ * CH * 2;     // 16 MB
    float* B    = (float*)(ws + o); o += (size_t)N_ * 256 * 4;    // 64 MB
    o += (size_t)48 << 20;                                        // pad so PQ fits
    u16* PQ = (u16*)pqb;   // N x 1024 bf16 = 128 MB, aliases x1b/B/pad (dead at GEMM3)

    // degree / norm / weights
    hipMemsetAsync(deg, 0, (size_t)N_ * 4, stream);
    k_deg <<<E_/256, 256, 0, stream>>>(ei, ea, deg);
    k_dis <<<N_/256, 256, 0, stream>>>(deg);
    k_norm<<<E_/256, 256, 0, stream>>>(ei, ea, deg, norm);
    k_concat<<<768, 256, 0, stream>>>(W1, V1, W2, V2, mw1, WV1t, WV2t, Mwt);

    dim3 g1(N_/128, 256/128);
    // layer 1: B = [m|v] = x @ [W1|V1]  (A fp32 converted in staging)
    mfma_gemm<1,0><<<g1, 256, 0, stream>>>(x, WV1t, B, 256, IN_CH);
    k_agg<1><<<G_, 256, 0, stream>>>(ei, norm, B, b1, nullptr, nullptr, x1b);
    // layer 2
    mfma_gemm<0,0><<<g1, 256, 0, stream>>>(x1b, WV2t, B, 256, CH);
    k_agg<2><<<G_, 256, 0, stream>>>(ei, norm, B, b2, out + OFF0, out + OFF5, x2b);
    // edge MLP hoisted to nodes: PQ = x2 @ Mw (N x 1024), bf16 out
    dim3 g3(N_/128, 1024/128);
    mfma_gemm<0,1><<<g3, 256, 0, stream>>>(x2b, Mwt, PQ, 1024, CH);
    k_edge<<<E_/4, 256, 0, stream>>>(ei, PQ, mb1, mw2, mb2, pred);
    // per-graph top-K partition + outputs
    k_sort<<<G_, 256, 0, stream>>>(pred, ei, ea, out);
    k_batch<<<N_/256, 256, 0, stream>>>(batch, out);
}

// Round 4
// 307.080 us; speedup vs baseline: 6.0384x; 1.0186x over previous
//
#include <hip/hip_runtime.h>
#include <hip/hip_bf16.h>
#include <stdint.h>

#define G_    1024
#define NPG   64
#define EPG   256
#define N_    (G_*NPG)     // 65536
#define E_    (G_*EPG)     // 262144
#define IN_CH 768
#define CH    128
#define KSEL  128
#define HID   512          // 4*CH

// ---- output layout (element offsets, all float32) ----
#define NCH  (N_*CH)       // 8388608
#define GK   (G_*KSEL)     // 131072
#define OFF0 0
#define OFF1 (OFF0 + NCH)
#define OFF2 (OFF1 + 2*GK)
#define OFF3 (OFF2 + GK)
#define OFF4 (OFF3 + GK)
#define OFF5 (OFF4 + N_)
#define OFF6 (OFF5 + NCH)
#define OFF7 (OFF6 + 2*GK)
#define OFF8 (OFF7 + GK)
#define OFF9 (OFF8 + GK)
#define OFF10 (OFF9 + N_)

typedef unsigned short u16;
typedef unsigned int   u32;
typedef __attribute__((ext_vector_type(8))) short bf16x8;
typedef __attribute__((ext_vector_type(4))) float f32x4;

__device__ __forceinline__ u16 f2bf(float x) {
    union { float f; u32 u; } v; v.f = x;
    u32 r = v.u + 0x7fffu + ((v.u >> 16) & 1u);   // RNE
    return (u16)(r >> 16);
}
__device__ __forceinline__ float bf2f(u32 h) {
    union { u32 u; float f; } v; v.u = h << 16; return v.f;
}

__global__ void k_deg(const int* __restrict__ ei, const float* __restrict__ ea,
                      float* __restrict__ deg) {
    int e = blockIdx.x * 256 + threadIdx.x;
    if (e < E_) atomicAdd(&deg[ei[E_ + e]], ea[e]);
}

__global__ void k_dis(float* __restrict__ deg) {
    int i = blockIdx.x * 256 + threadIdx.x;
    if (i < N_) { float d = deg[i]; deg[i] = d > 0.f ? 1.0f / sqrtf(d) : 0.f; }
}

__global__ void k_norm(const int* __restrict__ ei, const float* __restrict__ ea,
                       const float* __restrict__ dis, float* __restrict__ norm) {
    int e = blockIdx.x * 256 + threadIdx.x;
    if (e < E_) norm[e] = dis[ei[e]] * ea[e] * dis[ei[E_ + e]];
}

// Build TRANSPOSED bf16 weights:
//  WV1t (256x768): row c holds col c of [W1|V1]
//  WV2t (256x128): row c holds col c of [W2|V2]
//  Mwt (1024x128): row c, c<512 -> mw1[:,c] rows 0..127 ; c>=512 -> mw1 rows 128..255 col c-512
__global__ void k_concat(const float* __restrict__ W1, const float* __restrict__ V1,
                         const float* __restrict__ W2, const float* __restrict__ V2,
                         const float* __restrict__ mw1,
                         u16* __restrict__ WV1t, u16* __restrict__ WV2t,
                         u16* __restrict__ Mwt) {
    int i = blockIdx.x * 256 + threadIdx.x;
    if (i < 256 * IN_CH) {
        int c = i / IN_CH, r = i - c * IN_CH;
        WV1t[i] = f2bf(c < CH ? W1[r*CH + c] : V1[r*CH + (c - CH)]);
    }
    if (i < 256 * CH) {
        int c = i >> 7, r = i & 127;
        WV2t[i] = f2bf(c < CH ? W2[r*CH + c] : V2[r*CH + (c - CH)]);
    }
    if (i < 1024 * CH) {
        int c = i >> 7, r = i & 127;
        Mwt[i] = f2bf(c < HID ? mw1[r*HID + c] : mw1[(CH + r)*HID + (c - HID)]);
    }
}

// bf16 MFMA GEMM: C(MxN) = A(MxK) @ Bt(NxK)^T.  Tile 128x128, BK=32, 256 thr = 4 waves.
// 2-phase double-buffered pipeline: issue next tile's global loads (to regs)
// before the MFMA cluster, ds_write to the other buffer after, one barrier/step.
template<int A_F32, int C_BF16>
__global__ __launch_bounds__(256) void mfma_gemm(const void* __restrict__ Ap,
        const u16* __restrict__ Bt, void* __restrict__ Cp, int Nn, int K) {
    __shared__ u16 As[2][128 * 32];
    __shared__ u16 Bs[2][128 * 32];
    const int t = threadIdx.x;
    const int lane = t & 63, w = t >> 6;
    const int wr = (w >> 1) << 6, wc = (w & 1) << 6;
    const size_t bm = (size_t)blockIdx.x * 128;
    const size_t bn = (size_t)blockIdx.y * 128;
    const int r16 = lane & 15, kq = lane >> 4;
    // staging granules: 512 granules (128 rows x 4x16B); thread t owns t and t+256
    const int row0 = t >> 2,          c0 = t & 3;
    const int row1 = (t + 256) >> 2,  c1 = (t + 256) & 3;

    float4 alo0, ahi0, alo1, ahi1;      // A_F32 prefetch regs
    uint4  ab0, ab1;                    // A bf16 prefetch regs
    uint4  bb0, bb1;                    // B prefetch regs

    #define LOAD_TILE(k0)                                                           \
        do {                                                                        \
            if (A_F32) {                                                            \
                const float* ap0 = (const float*)Ap + (bm + row0) * (size_t)K + (k0) + c0 * 8; \
                alo0 = *(const float4*)ap0;  ahi0 = *(const float4*)(ap0 + 4);      \
                const float* ap1 = (const float*)Ap + (bm + row1) * (size_t)K + (k0) + c1 * 8; \
                alo1 = *(const float4*)ap1;  ahi1 = *(const float4*)(ap1 + 4);      \
            } else {                                                                \
                ab0 = *(const uint4*)((const u16*)Ap + (bm + row0) * (size_t)K + (k0) + c0 * 8); \
                ab1 = *(const uint4*)((const u16*)Ap + (bm + row1) * (size_t)K + (k0) + c1 * 8); \
            }                                                                       \
            bb0 = *(const uint4*)(Bt + (bn + row0) * (size_t)K + (k0) + c0 * 8);    \
            bb1 = *(const uint4*)(Bt + (bn + row1) * (size_t)K + (k0) + c1 * 8);    \
        } while (0)

    #define WRITE_TILE(buf)                                                         \
        do {                                                                        \
            int sc0 = c0 ^ (row0 & 3), sc1 = c1 ^ (row1 & 3);                       \
            uint4 va0, va1;                                                         \
            if (A_F32) {                                                            \
                union { uint4 q; u16 s[8]; } pk;                                    \
                pk.s[0]=f2bf(alo0.x); pk.s[1]=f2bf(alo0.y); pk.s[2]=f2bf(alo0.z); pk.s[3]=f2bf(alo0.w); \
                pk.s[4]=f2bf(ahi0.x); pk.s[5]=f2bf(ahi0.y); pk.s[6]=f2bf(ahi0.z); pk.s[7]=f2bf(ahi0.w); \
                va0 = pk.q;                                                         \
                pk.s[0]=f2bf(alo1.x); pk.s[1]=f2bf(alo1.y); pk.s[2]=f2bf(alo1.z); pk.s[3]=f2bf(alo1.w); \
                pk.s[4]=f2bf(ahi1.x); pk.s[5]=f2bf(ahi1.y); pk.s[6]=f2bf(ahi1.z); pk.s[7]=f2bf(ahi1.w); \
                va1 = pk.q;                                                         \
            } else { va0 = ab0; va1 = ab1; }                                        \
            *(uint4*)&As[buf][row0 * 32 + sc0 * 8] = va0;                           \
            *(uint4*)&Bs[buf][row0 * 32 + sc0 * 8] = bb0;                           \
            *(uint4*)&As[buf][row1 * 32 + sc1 * 8] = va1;                           \
            *(uint4*)&Bs[buf][row1 * 32 + sc1 * 8] = bb1;                           \
        } while (0)

    f32x4 acc[4][4];
    #pragma unroll
    for (int m = 0; m < 4; ++m)
        #pragma unroll
        for (int n = 0; n < 4; ++n)
            acc[m][n] = (f32x4){0.f, 0.f, 0.f, 0.f};

    LOAD_TILE(0);
    WRITE_TILE(0);
    __syncthreads();

    const int nk = K >> 5;
    for (int ki = 0; ki < nk; ++ki) {
        const int cur = ki & 1;
        if (ki + 1 < nk) LOAD_TILE((ki + 1) << 5);   // in flight during MFMA
        bf16x8 a[4], b[4];
        #pragma unroll
        for (int m = 0; m < 4; ++m) {
            int row = wr + m * 16 + r16;
            a[m] = *(const bf16x8*)&As[cur][row * 32 + ((kq ^ (row & 3)) * 8)];
        }
        #pragma unroll
        for (int n = 0; n < 4; ++n) {
            int row = wc + n * 16 + r16;
            b[n] = *(const bf16x8*)&Bs[cur][row * 32 + ((kq ^ (row & 3)) * 8)];
        }
        #pragma unroll
        for (int m = 0; m < 4; ++m)
            #pragma unroll
            for (int n = 0; n < 4; ++n)
                acc[m][n] = __builtin_amdgcn_mfma_f32_16x16x32_bf16(a[m], b[n], acc[m][n], 0, 0, 0);
        if (ki + 1 < nk) WRITE_TILE(cur ^ 1);        // vmcnt wait lands here
        __syncthreads();
    }
    #undef LOAD_TILE
    #undef WRITE_TILE

    // C/D layout: col = lane&15, row = (lane>>4)*4 + reg
    #pragma unroll
    for (int m = 0; m < 4; ++m) {
        #pragma unroll
        for (int j = 0; j < 4; ++j) {
            size_t row = bm + wr + m * 16 + kq * 4 + j;
            #pragma unroll
            for (int n = 0; n < 4; ++n) {
                size_t col = bn + wc + n * 16 + r16;
                if (C_BF16) ((u16*)Cp)[row * Nn + col] = f2bf(acc[m][n][j]);
                else        ((float*)Cp)[row * Nn + col] = acc[m][n][j];
            }
        }
    }
}

// Fused per-graph aggregation + epilogue.
// agg[c][ch] = sum_r A[r][c] * m[r][ch], via dense 64x64 LDS adjacency + MFMA.
// Then out = relu(agg + v + bias).  B holds [m|v] (N x 256 f32).
template<int LAYER>
__global__ __launch_bounds__(256) void k_agg(const int* __restrict__ ei,
        const float* __restrict__ norm, const float* __restrict__ B,
        const float* __restrict__ bias, float* __restrict__ out0,
        float* __restrict__ out5, u16* __restrict__ xb) {
    __shared__ float A_s[64 * 65];   // [r][c], padded
    __shared__ u16   Ms[64 * 132];   // m bf16 [r][ch], padded
    const int g = blockIdx.x, t = threadIdx.x;
    const int lane = t & 63, w = t >> 6;
    const int r16 = lane & 15, kq = lane >> 4;
    const size_t nbase = (size_t)g * 64;

    #pragma unroll
    for (int i = t; i < 64 * 65; i += 256) A_s[i] = 0.f;
    #pragma unroll
    for (int i = t; i < 64 * 32; i += 256) {
        int row = i >> 5, c4 = (i & 31) << 2;
        float4 mv = *(const float4*)(B + (nbase + row) * 256 + c4);
        union { uint2 d; u16 s[4]; } p;
        p.s[0] = f2bf(mv.x); p.s[1] = f2bf(mv.y);
        p.s[2] = f2bf(mv.z); p.s[3] = f2bf(mv.w);
        *(uint2*)&Ms[row * 132 + c4] = p.d;
    }
    __syncthreads();
    {   // scatter 256 edges into A_s[r][c] (duplicates possible -> atomic)
        int e = g * 256 + t;
        int r = ei[e] & 63, c = ei[E_ + e] & 63;
        atomicAdd(&A_s[r * 65 + c], norm[e]);
    }
    __syncthreads();

    const int n0 = w * 32;           // wave's ch chunk
    f32x4 acc[4][2];
    #pragma unroll
    for (int mt = 0; mt < 4; ++mt)
        #pragma unroll
        for (int nt = 0; nt < 2; ++nt)
            acc[mt][nt] = (f32x4){0.f, 0.f, 0.f, 0.f};

    union bfr { bf16x8 v; u16 s[8]; };
    #pragma unroll
    for (int ks = 0; ks < 2; ++ks) {
        bfr a[4], b[2];
        #pragma unroll
        for (int mt = 0; mt < 4; ++mt)
            #pragma unroll
            for (int i = 0; i < 8; ++i)
                a[mt].s[i] = f2bf(A_s[(ks*32 + kq*8 + i) * 65 + mt*16 + r16]);
        #pragma unroll
        for (int nt = 0; nt < 2; ++nt)
            #pragma unroll
            for (int i = 0; i < 8; ++i)
                b[nt].s[i] = Ms[(ks*32 + kq*8 + i) * 132 + n0 + nt*16 + r16];
        #pragma unroll
        for (int mt = 0; mt < 4; ++mt)
            #pragma unroll
            for (int nt = 0; nt < 2; ++nt)
                acc[mt][nt] = __builtin_amdgcn_mfma_f32_16x16x32_bf16(a[mt].v, b[nt].v, acc[mt][nt], 0, 0, 0);
    }
    // epilogue: C row = output node (c), col = ch
    #pragma unroll
    for (int mt = 0; mt < 4; ++mt) {
        #pragma unroll
        for (int j = 0; j < 4; ++j) {
            int c = mt * 16 + kq * 4 + j;
            size_t node = nbase + c;
            #pragma unroll
            for (int nt = 0; nt < 2; ++nt) {
                int ch = n0 + nt * 16 + r16;
                float v = B[node * 256 + 128 + ch] + bias[ch];
                float r = fmaxf(acc[mt][nt][j] + v, 0.f);
                if (LAYER == 1) {
                    xb[node * 128 + ch] = f2bf(r);
                } else {
                    out0[node * 128 + ch] = r;
                    out5[node * 128 + ch] = r;
                    xb[node * 128 + ch] = f2bf(r);
                }
            }
        }
    }
}

// pred[e] = mb2 + sum_j relu(P[row][j] + Q[col][j] + mb1[j]) * mw2[j]
// PQ: Nx1024 bf16, P = [0,512), Q = [512,1024). One wave per edge.
__global__ __launch_bounds__(256) void k_edge(const int* __restrict__ ei,
        const u16* __restrict__ PQ, const float* __restrict__ mb1,
        const float* __restrict__ mw2, const float* __restrict__ mb2,
        float* __restrict__ pred) {
    int wid = threadIdx.x >> 6, lane = threadIdx.x & 63;
    int e = blockIdx.x * 4 + wid;
    int r = ei[e], c = ei[E_ + e];
    uint4 up = *(const uint4*)(PQ + (size_t)r * 1024 + lane * 8);
    uint4 uq = *(const uint4*)(PQ + (size_t)c * 1024 + 512 + lane * 8);
    float4 b0 = *(const float4*)(mb1 + lane * 8);
    float4 b1 = *(const float4*)(mb1 + lane * 8 + 4);
    float4 w0 = *(const float4*)(mw2 + lane * 8);
    float4 w1 = *(const float4*)(mw2 + lane * 8 + 4);
    u32 pu[4] = {up.x, up.y, up.z, up.w};
    u32 qu[4] = {uq.x, uq.y, uq.z, uq.w};
    float bb[8] = {b0.x,b0.y,b0.z,b0.w,b1.x,b1.y,b1.z,b1.w};
    float ww[8] = {w0.x,w0.y,w0.z,w0.w,w1.x,w1.y,w1.z,w1.w};
    float s = 0.f;
    #pragma unroll
    for (int k = 0; k < 4; ++k) {
        float p0 = bf2f(pu[k] & 0xffffu), p1 = bf2f(pu[k] >> 16);
        float q0 = bf2f(qu[k] & 0xffffu), q1 = bf2f(qu[k] >> 16);
        float h0 = fmaxf(p0 + q0 + bb[2*k],     0.f);
        float h1 = fmaxf(p1 + q1 + bb[2*k + 1], 0.f);
        s += h0 * ww[2*k] + h1 * ww[2*k + 1];
    }
    #pragma unroll
    for (int m = 32; m >= 1; m >>= 1) s += __shfl_xor(s, m, 64);
    if (lane == 0) pred[e] = s + mb2[0];
}

// one block per graph: stable bitonic sort (desc by pred, ties by idx asc),
// then write causal/conf gathers + the full pred copy.
__global__ __launch_bounds__(256) void k_sort(const float* __restrict__ pred,
        const int* __restrict__ ei, const float* __restrict__ ea,
        float* __restrict__ out) {
    __shared__ float key[256];
    __shared__ int   idx[256];
    int g = blockIdx.x, t = threadIdx.x;
    int ebase = g * EPG;
    float p = pred[ebase + t];
    key[t] = p; idx[t] = t;
    for (int k2 = 2; k2 <= 256; k2 <<= 1) {
        for (int j = k2 >> 1; j >= 1; j >>= 1) {
            __syncthreads();
            int ixj = t ^ j;
            if (ixj > t) {
                float ka = key[t], kb = key[ixj];
                int   ia = idx[t], ib = idx[ixj];
                bool up = ((t & k2) == 0);
                bool a_before_b = (ka > kb) || (ka == kb && ia < ib);
                bool do_swap = up ? !a_before_b : a_before_b;
                if (do_swap) { key[t] = kb; key[ixj] = ka; idx[t] = ib; idx[ixj] = ia; }
            }
        }
    }
    __syncthreads();
    int el = idx[t];
    int eg = ebase + el;
    float pv = key[t];
    float r = (float)ei[eg];
    float c = (float)ei[E_ + eg];
    float av = ea[eg];
    if (t < KSEL) {
        int oo = g * KSEL + t;
        out[OFF1 + oo]      = r;
        out[OFF1 + GK + oo] = c;
        out[OFF2 + oo]      = av;
        out[OFF3 + oo]      = pv;
    } else {
        int oo = g * KSEL + (t - KSEL);
        out[OFF6 + oo]      = r;
        out[OFF6 + GK + oo] = c;
        out[OFF7 + oo]      = av;
        out[OFF8 + oo]      = -pv;
    }
    out[OFF10 + ebase + t] = p;
}

__global__ void k_batch(const int* __restrict__ batch, float* __restrict__ out) {
    int i = blockIdx.x * 256 + threadIdx.x;
    if (i < N_) { float b = (float)batch[i]; out[OFF4 + i] = b; out[OFF9 + i] = b; }
}

extern "C" void kernel_launch(void* const* d_in, const int* in_sizes, int n_in,
                              void* d_out, int out_size, void* d_ws, size_t ws_size,
                              hipStream_t stream) {
    const float* x     = (const float*)d_in[0];
    const int*   ei    = (const int*)  d_in[1];
    const float* ea    = (const float*)d_in[2];
    const int*   batch = (const int*)  d_in[3];
    const float* W1    = (const float*)d_in[4];
    const float* V1    = (const float*)d_in[5];
    const float* b1    = (const float*)d_in[6];
    const float* W2    = (const float*)d_in[7];
    const float* V2    = (const float*)d_in[8];
    const float* b2    = (const float*)d_in[9];
    const float* mw1   = (const float*)d_in[10];
    const float* mb1   = (const float*)d_in[11];
    const float* mw2   = (const float*)d_in[12];
    const float* mb2   = (const float*)d_in[13];
    float* out = (float*)d_out;

    char* ws = (char*)d_ws;
    size_t o = 0;
    float* deg  = (float*)(ws + o); o += (size_t)N_ * 4;          // 256 KB
    float* norm = (float*)(ws + o); o += (size_t)E_ * 4;          // 1 MB
    float* pred = (float*)(ws + o); o += (size_t)E_ * 4;          // 1 MB
    u16* WV1t   = (u16*)(ws + o);   o += (size_t)256 * IN_CH * 2; // 384 KB
    u16* WV2t   = (u16*)(ws + o);   o += (size_t)256 * CH * 2;    // 64 KB
    u16* Mwt    = (u16*)(ws + o);   o += (size_t)1024 * CH * 2;   // 256 KB
    u16* x2b    = (u16*)(ws + o);   o += (size_t)N_ * CH * 2;     // 16 MB
    char* pqb   = ws + o;                                         // PQ region start
    u16* x1b    = (u16*)(ws + o);   o += (size_t)N_ * CH * 2;     // 16 MB
    float* B    = (float*)(ws + o); o += (size_t)N_ * 256 * 4;    // 64 MB
    o += (size_t)48 << 20;                                        // pad so PQ fits
    u16* PQ = (u16*)pqb;   // N x 1024 bf16 = 128 MB, aliases x1b/B/pad (dead at GEMM3)

    // degree / norm / weights
    hipMemsetAsync(deg, 0, (size_t)N_ * 4, stream);
    k_deg <<<E_/256, 256, 0, stream>>>(ei, ea, deg);
    k_dis <<<N_/256, 256, 0, stream>>>(deg);
    k_norm<<<E_/256, 256, 0, stream>>>(ei, ea, deg, norm);
    k_concat<<<768, 256, 0, stream>>>(W1, V1, W2, V2, mw1, WV1t, WV2t, Mwt);

    dim3 g1(N_/128, 256/128);
    // layer 1: B = [m|v] = x @ [W1|V1]  (A fp32 converted in staging)
    mfma_gemm<1,0><<<g1, 256, 0, stream>>>(x, WV1t, B, 256, IN_CH);
    k_agg<1><<<G_, 256, 0, stream>>>(ei, norm, B, b1, nullptr, nullptr, x1b);
    // layer 2
    mfma_gemm<0,0><<<g1, 256, 0, stream>>>(x1b, WV2t, B, 256, CH);
    k_agg<2><<<G_, 256, 0, stream>>>(ei, norm, B, b2, out + OFF0, out + OFF5, x2b);
    // edge MLP hoisted to nodes: PQ = x2 @ Mw (N x 1024), bf16 out
    dim3 g3(N_/128, 1024/128);
    mfma_gemm<0,1><<<g3, 256, 0, stream>>>(x2b, Mwt, PQ, 1024, CH);
    k_edge<<<E_/4, 256, 0, stream>>>(ei, PQ, mb1, mw2, mb2, pred);
    // per-graph top-K partition + outputs
    k_sort<<<G_, 256, 0, stream>>>(pred, ei, ea, out);
    k_batch<<<N_/256, 256, 0, stream>>>(batch, out);
}